// Round 3
// baseline (595.813 us; speedup 1.0000x reference)
//
#include <hip/hip_runtime.h>
#include <hip/hip_bf16.h>

#define H_NUM 16
#define D_DIM 64
#define S_LEN 2048
#define EMB   1024
#define M_TOT 4096   // B * S_LEN

typedef unsigned short u16;
typedef unsigned int   u32;
typedef __attribute__((ext_vector_type(8))) short short8;   // 8 bf16 in 4 VGPRs
typedef __attribute__((ext_vector_type(4))) float f32x4;    // MFMA C/D

__device__ __forceinline__ u16 f2bf(float f) {
    union { float f; u32 u; } v; v.f = f;
    u32 r = v.u + 0x7fffu + ((v.u >> 16) & 1u);   // RNE
    return (u16)(r >> 16);
}

// pack 8 consecutive f32 (lo.x..hi.w) into 8 bf16 (RNE), as uint4 for LDS store
__device__ __forceinline__ uint4 pack8(float4 lo, float4 hi) {
    union { uint4 u4; __hip_bfloat162 h[4]; } r;
    r.h[0] = __float22bfloat162_rn(make_float2(lo.x, lo.y));
    r.h[1] = __float22bfloat162_rn(make_float2(lo.z, lo.w));
    r.h[2] = __float22bfloat162_rn(make_float2(hi.x, hi.y));
    r.h[3] = __float22bfloat162_rn(make_float2(hi.z, hi.w));
    return r.u4;
}

// ---------------------------------------------------------------------------
// Kernel A: P = X (4096x1024 f32) * W^T (f32 1024x1024), 128x128 tiles.
// z selects Wq/Wk/Wv. RoPE fused for z=0,1. Output layout [B,H,S,D] bf16.
// ---------------------------------------------------------------------------
__global__ __launch_bounds__(256) void qkv_rope_kernel(
    const float* __restrict__ x, const float* __restrict__ Wq,
    const float* __restrict__ Wk, const float* __restrict__ Wv,
    u16* __restrict__ qo, u16* __restrict__ ko, u16* __restrict__ vo)
{
    const int w = blockIdx.z;
    const float* W = (w == 0) ? Wq : (w == 1) ? Wk : Wv;
    u16*       out = (w == 0) ? qo : (w == 1) ? ko : vo;

    __shared__ __align__(16) u16 As[128][40];   // bf16 tiles, pitch 40 (+8 pad)
    __shared__ __align__(16) u16 Bs[128][40];

    const int tid   = threadIdx.x;
    const int lane  = tid & 63;
    const int wid   = tid >> 6;
    const int waveM = wid >> 1;          // 2x2 waves of 64x64
    const int waveN = wid & 1;
    const int col16 = lane & 15;
    const int quad  = lane >> 4;

    const int m0 = blockIdx.y * 128;
    const int n0 = blockIdx.x * 128;

    f32x4 acc[4][4];
    const f32x4 zero4 = {0.f, 0.f, 0.f, 0.f};
    for (int i = 0; i < 4; i++) for (int j = 0; j < 4; j++) acc[i][j] = zero4;

    const int lrow = tid >> 2;        // 0..63
    const int lcol = (tid & 3) * 8;   // 0,8,16,24  (8 f32 each → BK=32)

    for (int k0 = 0; k0 < EMB; k0 += 32) {
        const float* pa0 = x + (size_t)(m0 + lrow)      * EMB + k0 + lcol;
        const float* pa1 = x + (size_t)(m0 + 64 + lrow) * EMB + k0 + lcol;
        const float* pb0 = W + (size_t)(n0 + lrow)      * EMB + k0 + lcol;
        const float* pb1 = W + (size_t)(n0 + 64 + lrow) * EMB + k0 + lcol;
        uint4 a0 = pack8(*(const float4*)pa0, *(const float4*)(pa0 + 4));
        uint4 a1 = pack8(*(const float4*)pa1, *(const float4*)(pa1 + 4));
        uint4 b0 = pack8(*(const float4*)pb0, *(const float4*)(pb0 + 4));
        uint4 b1 = pack8(*(const float4*)pb1, *(const float4*)(pb1 + 4));
        __syncthreads();   // previous iteration's frag reads done
        *(uint4*)(&As[lrow][lcol])      = a0;
        *(uint4*)(&As[64 + lrow][lcol]) = a1;
        *(uint4*)(&Bs[lrow][lcol])      = b0;
        *(uint4*)(&Bs[64 + lrow][lcol]) = b1;
        __syncthreads();

        short8 af[4], bf[4];
        for (int mt = 0; mt < 4; mt++)
            af[mt] = *(const short8*)(&As[waveM * 64 + mt * 16 + col16][quad * 8]);
        for (int nt = 0; nt < 4; nt++)
            bf[nt] = *(const short8*)(&Bs[waveN * 64 + nt * 16 + col16][quad * 8]);
        for (int mt = 0; mt < 4; mt++)
            for (int nt = 0; nt < 4; nt++)
                acc[mt][nt] = __builtin_amdgcn_mfma_f32_16x16x32_bf16(
                    af[mt], bf[nt], acc[mt][nt], 0, 0, 0);
    }

    // Epilogue: C/D layout col=lane&15, row=quad*4+r.
    for (int mt = 0; mt < 4; mt++) {
        for (int r = 0; r < 4; r++) {
            const int m_g = m0 + waveM * 64 + mt * 16 + quad * 4 + r;
            const int b = m_g >> 11;          // /2048
            const int s = m_g & 2047;
            if (w == 2) {
                for (int nt = 0; nt < 4; nt++) {
                    const int n_g = n0 + waveN * 64 + nt * 16 + col16;
                    const int h = n_g >> 6, d = n_g & 63;
                    out[(((size_t)(b * H_NUM + h) * S_LEN + s) << 6) + d] =
                        f2bf(acc[mt][nt][r]);
                }
            } else {
                // RoPE: pair (d, d+32) is (nt, nt+2), same lane, same reg.
                for (int nt = 0; nt < 2; nt++) {
                    const int n_g = n0 + waveN * 64 + nt * 16 + col16;
                    const int h = n_g >> 6, d = n_g & 63;   // d in [0,32)
                    // inv_freq = 10000^(-d/32);  0.28782... = ln(10000)/32
                    const float ang = (float)s * __expf(-(float)d * 0.28782313662425573f);
                    const float c  = cosf(ang);
                    const float sn = sinf(ang);
                    const float lo = acc[mt][nt][r];
                    const float hi = acc[mt][nt + 2][r];
                    const size_t base = ((size_t)(b * H_NUM + h) * S_LEN + s) << 6;
                    out[base + d]      = f2bf(lo * c - hi * sn);
                    out[base + d + 32] = f2bf(hi * c + lo * sn);
                }
            }
        }
    }
}

// ---------------------------------------------------------------------------
// Kernel B: causal flash attention (bf16 in ws). One block = 128 q-rows of
// one (b,h). 4 waves, each owns 32 q-rows. K/V tiles of 64 keys.
// ---------------------------------------------------------------------------
__global__ __launch_bounds__(256) void attn_kernel(
    const u16* __restrict__ q, const u16* __restrict__ k,
    const u16* __restrict__ v, u16* __restrict__ ctx)
{
    __shared__ __align__(16) u16 Qs[128][72];
    __shared__ __align__(16) u16 Ks[64][72];
    __shared__ __align__(16) u16 VTs[64][72];     // VT[d][t]
    __shared__ __align__(16) u16 Ps[4][32][72];   // per-wave P

    const int tid   = threadIdx.x;
    const int lane  = tid & 63;
    const int wid   = tid >> 6;
    const int col16 = lane & 15;
    const int quad  = lane >> 4;

    const int bh    = blockIdx.y;          // b*16 + h
    const int qb    = blockIdx.x;          // 0..15
    const int qBase = qb * 128;
    const size_t bhOff = (size_t)bh * S_LEN * D_DIM;

    // stage Q tile (128x64): 32 rows/pass x full 64 cols
    {
        const int row = tid >> 3;          // 0..31
        const int c8  = (tid & 7) * 8;     // 0..56
        for (int p = 0; p < 4; p++)
            *(uint4*)(&Qs[p * 32 + row][c8]) =
                *(const uint4*)(q + bhOff + (size_t)(qBase + p * 32 + row) * D_DIM + c8);
    }
    __syncthreads();

    // Q fragments held in registers for the whole loop
    short8 qf[2][2];
    for (int mt = 0; mt < 2; mt++)
        for (int ks = 0; ks < 2; ks++)
            qf[mt][ks] = *(const short8*)(&Qs[wid * 32 + mt * 16 + col16][ks * 32 + quad * 8]);

    f32x4 O[2][4];
    const f32x4 zero4 = {0.f, 0.f, 0.f, 0.f};
    for (int i = 0; i < 2; i++) for (int j = 0; j < 4; j++) O[i][j] = zero4;
    float mrun[2][4], lrun[2][4];
    for (int i = 0; i < 2; i++)
        for (int r = 0; r < 4; r++) { mrun[i][r] = -INFINITY; lrun[i][r] = 0.f; }

    const int rowMax = qBase + wid * 32 + 31;   // last q-row this wave owns
    const int ktEnd  = qb * 2 + 1;

    for (int kt = 0; kt <= ktEnd; kt++) {
        __syncthreads();
        {   // stage K (row-major) and V transposed: 32 rows/pass x full 64 cols
            const int t2 = tid >> 3;           // 0..31
            const int c8 = (tid & 7) * 8;      // 0..56
            for (int p = 0; p < 2; p++) {
                const int t = p * 32 + t2;
                const size_t g = bhOff + (size_t)(kt * 64 + t) * D_DIM + c8;
                *(uint4*)(&Ks[t][c8]) = *(const uint4*)(k + g);
                uint4 vv = *(const uint4*)(v + g);
                const u16* vs = (const u16*)&vv;
                for (int j = 0; j < 8; j++) VTs[c8 + j][t] = vs[j];
            }
        }
        __syncthreads();

        if (kt * 64 > rowMax) continue;   // wave fully masked (no barrier inside)

        // S = Q K^T (K rows are the B^T operand)
        f32x4 sc[2][4];
        for (int mt = 0; mt < 2; mt++) for (int nt = 0; nt < 4; nt++) sc[mt][nt] = zero4;
        for (int ks = 0; ks < 2; ks++) {
            short8 kf[4];
            for (int nt = 0; nt < 4; nt++)
                kf[nt] = *(const short8*)(&Ks[nt * 16 + col16][ks * 32 + quad * 8]);
            for (int mt = 0; mt < 2; mt++)
                for (int nt = 0; nt < 4; nt++)
                    sc[mt][nt] = __builtin_amdgcn_mfma_f32_16x16x32_bf16(
                        qf[mt][ks], kf[nt], sc[mt][nt], 0, 0, 0);
        }

        // causal mask + online softmax (row lives in 16 lanes of a quad)
        float alpha[2][4];
        for (int mt = 0; mt < 2; mt++) {
            for (int r = 0; r < 4; r++) {
                const int qg = qBase + wid * 32 + mt * 16 + quad * 4 + r;
                float mx = -INFINITY;
                for (int nt = 0; nt < 4; nt++) {
                    const int kg = kt * 64 + nt * 16 + col16;
                    float sv = sc[mt][nt][r] * 0.125f;   // 1/sqrt(64)
                    sv = (kg > qg) ? -INFINITY : sv;
                    sc[mt][nt][r] = sv;
                    mx = fmaxf(mx, sv);
                }
                for (int o = 1; o < 16; o <<= 1) mx = fmaxf(mx, __shfl_xor(mx, o));
                const float mnew = fmaxf(mrun[mt][r], mx);
                const float a = __expf(mrun[mt][r] - mnew);
                mrun[mt][r] = mnew;
                float rs = 0.f;
                for (int nt = 0; nt < 4; nt++) {
                    const float p = __expf(sc[mt][nt][r] - mnew);
                    sc[mt][nt][r] = p;
                    rs += p;
                }
                for (int o = 1; o < 16; o <<= 1) rs += __shfl_xor(rs, o);
                lrun[mt][r] = a * lrun[mt][r] + rs;
                alpha[mt][r] = a;
            }
        }

        // P -> wave-private LDS (C-layout to row-major), then read back as A-frags
        for (int mt = 0; mt < 2; mt++)
            for (int r = 0; r < 4; r++)
                for (int nt = 0; nt < 4; nt++)
                    Ps[wid][mt * 16 + quad * 4 + r][nt * 16 + col16] = f2bf(sc[mt][nt][r]);

        for (int mt = 0; mt < 2; mt++)
            for (int dt = 0; dt < 4; dt++)
                for (int r = 0; r < 4; r++)
                    O[mt][dt][r] *= alpha[mt][r];

        for (int ks = 0; ks < 2; ks++) {
            short8 pf[2], vf[4];
            for (int mt = 0; mt < 2; mt++)
                pf[mt] = *(const short8*)(&Ps[wid][mt * 16 + col16][ks * 32 + quad * 8]);
            for (int dt = 0; dt < 4; dt++)
                vf[dt] = *(const short8*)(&VTs[dt * 16 + col16][ks * 32 + quad * 8]);
            for (int mt = 0; mt < 2; mt++)
                for (int dt = 0; dt < 4; dt++)
                    O[mt][dt] = __builtin_amdgcn_mfma_f32_16x16x32_bf16(
                        pf[mt], vf[dt], O[mt][dt], 0, 0, 0);
        }
    }

    // epilogue: ctx[b][s][h*64+d] = O / l   (bf16)
    const int b = bh >> 4, h = bh & 15;
    for (int mt = 0; mt < 2; mt++) {
        for (int r = 0; r < 4; r++) {
            const int s = qBase + wid * 32 + mt * 16 + quad * 4 + r;
            const float inv = 1.0f / lrun[mt][r];
            const size_t base = ((size_t)(b * S_LEN + s)) * EMB + h * 64;
            for (int dt = 0; dt < 4; dt++)
                ctx[base + dt * 16 + col16] = f2bf(O[mt][dt][r] * inv);
        }
    }
}

// ---------------------------------------------------------------------------
// Kernel C: out(f32) = ctx (4096x1024 bf16) * Wo^T (f32).
// ---------------------------------------------------------------------------
__global__ __launch_bounds__(256) void proj_kernel(
    const u16* __restrict__ X, const float* __restrict__ W, float* __restrict__ out)
{
    __shared__ __align__(16) u16 As[128][40];
    __shared__ __align__(16) u16 Bs[128][40];

    const int tid   = threadIdx.x;
    const int lane  = tid & 63;
    const int wid   = tid >> 6;
    const int waveM = wid >> 1;
    const int waveN = wid & 1;
    const int col16 = lane & 15;
    const int quad  = lane >> 4;

    const int m0 = blockIdx.y * 128;
    const int n0 = blockIdx.x * 128;

    f32x4 acc[4][4];
    const f32x4 zero4 = {0.f, 0.f, 0.f, 0.f};
    for (int i = 0; i < 4; i++) for (int j = 0; j < 4; j++) acc[i][j] = zero4;

    const int lrow = tid >> 2;
    const int lcol = (tid & 3) * 8;

    for (int k0 = 0; k0 < EMB; k0 += 32) {
        uint4 a0 = *(const uint4*)(X + (size_t)(m0 + lrow)      * EMB + k0 + lcol);
        uint4 a1 = *(const uint4*)(X + (size_t)(m0 + 64 + lrow) * EMB + k0 + lcol);
        const float* pb0 = W + (size_t)(n0 + lrow)      * EMB + k0 + lcol;
        const float* pb1 = W + (size_t)(n0 + 64 + lrow) * EMB + k0 + lcol;
        uint4 b0 = pack8(*(const float4*)pb0, *(const float4*)(pb0 + 4));
        uint4 b1 = pack8(*(const float4*)pb1, *(const float4*)(pb1 + 4));
        __syncthreads();
        *(uint4*)(&As[lrow][lcol])      = a0;
        *(uint4*)(&As[64 + lrow][lcol]) = a1;
        *(uint4*)(&Bs[lrow][lcol])      = b0;
        *(uint4*)(&Bs[64 + lrow][lcol]) = b1;
        __syncthreads();

        short8 af[4], bf[4];
        for (int mt = 0; mt < 4; mt++)
            af[mt] = *(const short8*)(&As[waveM * 64 + mt * 16 + col16][quad * 8]);
        for (int nt = 0; nt < 4; nt++)
            bf[nt] = *(const short8*)(&Bs[waveN * 64 + nt * 16 + col16][quad * 8]);
        for (int mt = 0; mt < 4; mt++)
            for (int nt = 0; nt < 4; nt++)
                acc[mt][nt] = __builtin_amdgcn_mfma_f32_16x16x32_bf16(
                    af[mt], bf[nt], acc[mt][nt], 0, 0, 0);
    }

    for (int mt = 0; mt < 4; mt++)
        for (int r = 0; r < 4; r++) {
            const int m_g = m0 + waveM * 64 + mt * 16 + quad * 4 + r;
            for (int nt = 0; nt < 4; nt++) {
                const int n_g = n0 + waveN * 64 + nt * 16 + col16;
                out[(size_t)m_g * EMB + n_g] = acc[mt][nt][r];   // f32 store
            }
        }
}

// ---------------------------------------------------------------------------
extern "C" void kernel_launch(void* const* d_in, const int* in_sizes, int n_in,
                              void* d_out, int out_size, void* d_ws, size_t ws_size,
                              hipStream_t stream)
{
    const float* x  = (const float*)d_in[0];
    const float* Wq = (const float*)d_in[1];
    const float* Wk = (const float*)d_in[2];
    const float* Wv = (const float*)d_in[3];
    const float* Wo = (const float*)d_in[4];

    u16* ws = (u16*)d_ws;
    const size_t SZ = (size_t)M_TOT * EMB;   // 4M elems each (bf16)
    u16* q   = ws;
    u16* k   = ws + SZ;
    u16* v   = ws + 2 * SZ;
    u16* ctx = ws + 3 * SZ;

    qkv_rope_kernel<<<dim3(8, 32, 3), 256, 0, stream>>>(x, Wq, Wk, Wv, q, k, v);
    attn_kernel<<<dim3(16, 32), 256, 0, stream>>>(q, k, v, ctx);
    proj_kernel<<<dim3(8, 32), 256, 0, stream>>>(ctx, Wo, (float*)d_out);
}